// Round 1
// baseline (1689.631 us; speedup 1.0000x reference)
//
#include <hip/hip_runtime.h>

#define NDIM 256

// ---------------- CSR build ----------------

__global__ void k_deg(const int* __restrict__ dst, int* __restrict__ deg, int E) {
    int i = blockIdx.x * blockDim.x + threadIdx.x;
    if (i < E) atomicAdd(&deg[dst[i]], 1);
}

__global__ void k_partial(const int* __restrict__ deg, int* __restrict__ partial, int N) {
    __shared__ int sm[256];
    int i = blockIdx.x * 256 + threadIdx.x;
    sm[threadIdx.x] = (i < N) ? deg[i] : 0;
    __syncthreads();
    for (int s = 128; s > 0; s >>= 1) {
        if (threadIdx.x < s) sm[threadIdx.x] += sm[threadIdx.x + s];
        __syncthreads();
    }
    if (threadIdx.x == 0) partial[blockIdx.x] = sm[0];
}

__global__ void k_scan_partial(int* partial, int nb) {
    __shared__ int sm[512];
    int t = threadIdx.x;
    int v = (t < nb) ? partial[t] : 0;
    sm[t] = v;
    __syncthreads();
    for (int off = 1; off < 512; off <<= 1) {
        int u = (t >= off) ? sm[t - off] : 0;
        __syncthreads();
        sm[t] += u;
        __syncthreads();
    }
    if (t < nb) partial[t] = sm[t] - v;   // exclusive
}

__global__ void k_scan_block(const int* __restrict__ deg, const int* __restrict__ partial,
                             int* __restrict__ offsets, int* __restrict__ cursor,
                             float* __restrict__ invdeg, int N) {
    __shared__ int sm[256];
    int t = threadIdx.x;
    int i = blockIdx.x * 256 + t;
    int v = (i < N) ? deg[i] : 0;
    sm[t] = v;
    __syncthreads();
    for (int off = 1; off < 256; off <<= 1) {
        int u = (t >= off) ? sm[t - off] : 0;
        __syncthreads();
        sm[t] += u;
        __syncthreads();
    }
    if (i < N) {
        int excl = sm[t] - v + partial[blockIdx.x];
        offsets[i] = excl;
        cursor[i]  = excl;
        invdeg[i]  = (v > 0) ? (1.0f / (float)v) : 0.0f;
    }
}

__global__ void k_place(const int* __restrict__ src, const int* __restrict__ dst,
                        int* __restrict__ cursor, int* __restrict__ srcsorted, int E) {
    int i = blockIdx.x * blockDim.x + threadIdx.x;
    if (i < E) {
        int p = atomicAdd(&cursor[dst[i]], 1);
        srcsorted[p] = src[i];
    }
}

// ---------------- aggregation: one wave per dst node, no f32 atomics ----------------

__global__ void k_aggr(const float* __restrict__ x, const int* __restrict__ srcsorted,
                       const int* __restrict__ offsets, const int* __restrict__ deg,
                       const float* __restrict__ invdeg, float* __restrict__ neigh, int N) {
    int node = blockIdx.x * 4 + (threadIdx.x >> 6);
    if (node >= N) return;
    int lane = threadIdx.x & 63;
    int beg = offsets[node];
    int d   = deg[node];
    float4 acc = make_float4(0.f, 0.f, 0.f, 0.f);
    int j = 0;
    for (; j + 3 < d; j += 4) {
        int s0 = srcsorted[beg + j + 0];
        int s1 = srcsorted[beg + j + 1];
        int s2 = srcsorted[beg + j + 2];
        int s3 = srcsorted[beg + j + 3];
        float4 v0 = *(const float4*)(x + (size_t)s0 * NDIM + lane * 4);
        float4 v1 = *(const float4*)(x + (size_t)s1 * NDIM + lane * 4);
        float4 v2 = *(const float4*)(x + (size_t)s2 * NDIM + lane * 4);
        float4 v3 = *(const float4*)(x + (size_t)s3 * NDIM + lane * 4);
        acc.x += v0.x + v1.x + v2.x + v3.x;
        acc.y += v0.y + v1.y + v2.y + v3.y;
        acc.z += v0.z + v1.z + v2.z + v3.z;
        acc.w += v0.w + v1.w + v2.w + v3.w;
    }
    for (; j < d; ++j) {
        int s = srcsorted[beg + j];
        float4 v = *(const float4*)(x + (size_t)s * NDIM + lane * 4);
        acc.x += v.x; acc.y += v.y; acc.z += v.z; acc.w += v.w;
    }
    float sc = invdeg[node];
    acc.x *= sc; acc.y *= sc; acc.z *= sc; acc.w *= sc;
    *(float4*)(neigh + (size_t)node * NDIM + lane * 4) = acc;
}

// ---------------- fused dual-source SGEMM: C = A1@B1 + A2@B2 + bias (+relu) ----------------
// M x 256 @ 256 x 256 (twice), BM=BN=64, BK=16, 256 threads, 4x4 microtile.

template <int RELU>
__global__ __launch_bounds__(256) void k_gemm(
        const float* __restrict__ A1, const float* __restrict__ B1,
        const float* __restrict__ A2, const float* __restrict__ B2,
        const float* __restrict__ bias, float* __restrict__ C, int M) {
    __shared__ float As[16][68];   // [k][m], stride 68 floats = 272B (16B aligned)
    __shared__ float Bs[16][68];   // [k][n]
    int tid = threadIdx.x;
    int tx = tid & 15;             // n direction
    int ty = tid >> 4;             // m direction
    int row0 = blockIdx.x * 64;
    int col0 = blockIdx.y * 64;
    float acc[4][4] = {};

    int am  = tid >> 2;            // 0..63 row in tile
    int akq = tid & 3;             // k-quad
    int bk  = tid >> 4;            // 0..15 k row
    int bn  = (tid & 15) * 4;      // col quad

    for (int pair = 0; pair < 2; ++pair) {
        const float* A = pair ? A2 : A1;
        const float* B = pair ? B2 : B1;
        for (int k0 = 0; k0 < NDIM; k0 += 16) {
            int grow = row0 + am;
            float4 av = make_float4(0.f, 0.f, 0.f, 0.f);
            if (grow < M) av = *(const float4*)(A + (size_t)grow * NDIM + k0 + akq * 4);
            float4 bv = *(const float4*)(B + (size_t)(k0 + bk) * NDIM + col0 + bn);
            __syncthreads();   // prev-iter LDS reads done before overwrite
            As[akq * 4 + 0][am] = av.x;
            As[akq * 4 + 1][am] = av.y;
            As[akq * 4 + 2][am] = av.z;
            As[akq * 4 + 3][am] = av.w;
            *(float4*)&Bs[bk][bn] = bv;
            __syncthreads();
#pragma unroll
            for (int k = 0; k < 16; ++k) {
                float4 a = *(const float4*)&As[k][ty * 4];
                float4 b = *(const float4*)&Bs[k][tx * 4];
                float ar[4] = {a.x, a.y, a.z, a.w};
                float br[4] = {b.x, b.y, b.z, b.w};
#pragma unroll
                for (int i = 0; i < 4; ++i)
#pragma unroll
                    for (int jj = 0; jj < 4; ++jj)
                        acc[i][jj] += ar[i] * br[jj];
            }
        }
    }

    float4 bb = *(const float4*)(bias + col0 + tx * 4);
#pragma unroll
    for (int i = 0; i < 4; ++i) {
        int row = row0 + ty * 4 + i;
        if (row < M) {
            float4 o;
            o.x = acc[i][0] + bb.x;
            o.y = acc[i][1] + bb.y;
            o.z = acc[i][2] + bb.z;
            o.w = acc[i][3] + bb.w;
            if (RELU) {
                o.x = fmaxf(o.x, 0.f); o.y = fmaxf(o.y, 0.f);
                o.z = fmaxf(o.z, 0.f); o.w = fmaxf(o.w, 0.f);
            }
            *(float4*)(C + (size_t)row * NDIM + col0 + tx * 4) = o;
        }
    }
}

__global__ void k_copy(const float4* __restrict__ in, float4* __restrict__ out, int n4) {
    int i = blockIdx.x * blockDim.x + threadIdx.x;
    if (i < n4) out[i] = in[i];
}

// ---------------- launch ----------------

extern "C" void kernel_launch(void* const* d_in, const int* in_sizes, int n_in,
                              void* d_out, int out_size, void* d_ws, size_t ws_size,
                              hipStream_t stream) {
    const float* feat = (const float*)d_in[0];
    const int*   src  = (const int*)d_in[1];
    const int*   dst  = (const int*)d_in[2];
    const float* Ws0  = (const float*)d_in[3];
    const float* Wn0  = (const float*)d_in[4];
    const float* b0   = (const float*)d_in[5];
    const float* Ws1  = (const float*)d_in[6];
    const float* Wn1  = (const float*)d_in[7];
    const float* b1   = (const float*)d_in[8];

    const int N = in_sizes[0] / NDIM;   // 100000
    const int E = in_sizes[1];          // 1600000

    float* out    = (float*)d_out;
    float* out_x  = out;                          // region 1: feat passthrough
    float* out_a1 = out + (size_t)N * NDIM;       // region 2: relu(h1)
    float* out_h2 = out + 2 * (size_t)N * NDIM;   // region 3: h2

    // scratch (~8 MB): deg | offsets | cursor | invdeg | partial | srcsorted
    int*   deg       = (int*)d_ws;
    int*   offsets   = deg + N;
    int*   cursor    = offsets + N;
    float* invdeg    = (float*)(cursor + N);
    int*   partial   = (int*)(invdeg + N);
    int*   srcsorted = partial + 512;

    // neigh accumulators live temporarily in the not-yet-final output regions
    float* neigh1 = out_h2;   // overwritten later by gemm2 output
    float* neigh2 = out_x;    // overwritten later by feat copy

    hipMemsetAsync(deg, 0, (size_t)N * sizeof(int), stream);

    int nb = (N + 255) / 256;
    k_deg<<<(E + 255) / 256, 256, 0, stream>>>(dst, deg, E);
    k_partial<<<nb, 256, 0, stream>>>(deg, partial, N);
    k_scan_partial<<<1, 512, 0, stream>>>(partial, nb);
    k_scan_block<<<nb, 256, 0, stream>>>(deg, partial, offsets, cursor, invdeg, N);
    k_place<<<(E + 255) / 256, 256, 0, stream>>>(src, dst, cursor, srcsorted, E);

    dim3 gg((N + 63) / 64, NDIM / 64);

    // layer 1
    k_aggr<<<(N + 3) / 4, 256, 0, stream>>>(feat, srcsorted, offsets, deg, invdeg, neigh1, N);
    k_gemm<1><<<gg, 256, 0, stream>>>(feat, Ws0, neigh1, Wn0, b0, out_a1, N);

    // layer 2
    k_aggr<<<(N + 3) / 4, 256, 0, stream>>>(out_a1, srcsorted, offsets, deg, invdeg, neigh2, N);
    k_gemm<0><<<gg, 256, 0, stream>>>(out_a1, Ws1, neigh2, Wn1, b1, out_h2, N);

    // feat passthrough (after gemm2 consumed neigh2 from this region)
    int n4 = N * NDIM / 4;
    k_copy<<<(n4 + 255) / 256, 256, 0, stream>>>((const float4*)feat, (float4*)out_x, n4);
}

// Round 2
// 997.921 us; speedup vs baseline: 1.6932x; 1.6932x over previous
//
#include <hip/hip_runtime.h>
#include <hip/hip_bf16.h>
#include <stdint.h>

#define NDIM 256

typedef __bf16 bf16_t;
typedef __bf16 bf16x8 __attribute__((ext_vector_type(8)));
typedef float f32x4 __attribute__((ext_vector_type(4)));

__device__ __forceinline__ float bf2f(uint16_t u) {
    union { uint32_t i; float f; } v; v.i = ((uint32_t)u) << 16; return v.f;
}
__device__ __forceinline__ uint16_t f2bf(float f) {
    union { float f; uint32_t i; } v; v.f = f;
    uint32_t r = v.i + 0x7fff + ((v.i >> 16) & 1);
    return (uint16_t)(r >> 16);
}

// ---------------- CSR build ----------------

__global__ void k_deg(const int* __restrict__ dst, int* __restrict__ deg, int E) {
    int i = blockIdx.x * blockDim.x + threadIdx.x;
    if (i < E) atomicAdd(&deg[dst[i]], 1);
}

__global__ void k_partial(const int* __restrict__ deg, int* __restrict__ partial, int N) {
    __shared__ int sm[256];
    int i = blockIdx.x * 256 + threadIdx.x;
    sm[threadIdx.x] = (i < N) ? deg[i] : 0;
    __syncthreads();
    for (int s = 128; s > 0; s >>= 1) {
        if (threadIdx.x < s) sm[threadIdx.x] += sm[threadIdx.x + s];
        __syncthreads();
    }
    if (threadIdx.x == 0) partial[blockIdx.x] = sm[0];
}

__global__ void k_scan_partial(int* partial, int nb) {
    __shared__ int sm[512];
    int t = threadIdx.x;
    int v = (t < nb) ? partial[t] : 0;
    sm[t] = v;
    __syncthreads();
    for (int off = 1; off < 512; off <<= 1) {
        int u = (t >= off) ? sm[t - off] : 0;
        __syncthreads();
        sm[t] += u;
        __syncthreads();
    }
    if (t < nb) partial[t] = sm[t] - v;   // exclusive
}

__global__ void k_scan_block(const int* __restrict__ deg, const int* __restrict__ partial,
                             int* __restrict__ offsets, int* __restrict__ cursor,
                             float* __restrict__ invdeg, int N) {
    __shared__ int sm[256];
    int t = threadIdx.x;
    int i = blockIdx.x * 256 + t;
    int v = (i < N) ? deg[i] : 0;
    sm[t] = v;
    __syncthreads();
    for (int off = 1; off < 256; off <<= 1) {
        int u = (t >= off) ? sm[t - off] : 0;
        __syncthreads();
        sm[t] += u;
        __syncthreads();
    }
    if (i < N) {
        int excl = sm[t] - v + partial[blockIdx.x];
        offsets[i] = excl;
        cursor[i]  = excl;
        invdeg[i]  = (v > 0) ? (1.0f / (float)v) : 0.0f;
    }
}

__global__ void k_place(const int* __restrict__ src, const int* __restrict__ dst,
                        int* __restrict__ cursor, int* __restrict__ srcsorted, int E) {
    int i = blockIdx.x * blockDim.x + threadIdx.x;
    if (i < E) {
        int p = atomicAdd(&cursor[dst[i]], 1);
        srcsorted[p] = src[i];
    }
}

// ---------------- conversions ----------------

__global__ void k_cvt(const float4* __restrict__ in, ushort4* __restrict__ out, int n4) {
    int i = blockIdx.x * blockDim.x + threadIdx.x;
    if (i < n4) {
        float4 v = in[i];
        ushort4 o;
        o.x = f2bf(v.x); o.y = f2bf(v.y); o.z = f2bf(v.z); o.w = f2bf(v.w);
        out[i] = o;
    }
}

// W[k][n] f32 -> Wt[n][k] bf16  (256x256)
__global__ void k_wt(const float* __restrict__ W, uint16_t* __restrict__ Wt) {
    int n = blockIdx.x, k = threadIdx.x;
    Wt[n * NDIM + k] = f2bf(W[k * NDIM + n]);
}

// ---------------- aggregation (bf16 in/out, f32 accumulate, wave per node) ----------------

__global__ __launch_bounds__(256) void k_aggr(
        const uint16_t* __restrict__ x, const int* __restrict__ srcsorted,
        const int* __restrict__ offsets, const int* __restrict__ deg,
        const float* __restrict__ invdeg, uint16_t* __restrict__ neigh, int N) {
    int node = blockIdx.x * 4 + (threadIdx.x >> 6);
    if (node >= N) return;
    int lane = threadIdx.x & 63;
    int beg = offsets[node];
    int d   = deg[node];
    float a0 = 0.f, a1 = 0.f, a2 = 0.f, a3 = 0.f;
    int j = 0;
    for (; j + 4 <= d; j += 4) {
        int s0 = srcsorted[beg + j + 0];
        int s1 = srcsorted[beg + j + 1];
        int s2 = srcsorted[beg + j + 2];
        int s3 = srcsorted[beg + j + 3];
        ushort4 v0 = *(const ushort4*)(x + (size_t)s0 * NDIM + lane * 4);
        ushort4 v1 = *(const ushort4*)(x + (size_t)s1 * NDIM + lane * 4);
        ushort4 v2 = *(const ushort4*)(x + (size_t)s2 * NDIM + lane * 4);
        ushort4 v3 = *(const ushort4*)(x + (size_t)s3 * NDIM + lane * 4);
        a0 += bf2f(v0.x) + bf2f(v1.x) + bf2f(v2.x) + bf2f(v3.x);
        a1 += bf2f(v0.y) + bf2f(v1.y) + bf2f(v2.y) + bf2f(v3.y);
        a2 += bf2f(v0.z) + bf2f(v1.z) + bf2f(v2.z) + bf2f(v3.z);
        a3 += bf2f(v0.w) + bf2f(v1.w) + bf2f(v2.w) + bf2f(v3.w);
    }
    for (; j < d; ++j) {
        int s = srcsorted[beg + j];
        ushort4 v = *(const ushort4*)(x + (size_t)s * NDIM + lane * 4);
        a0 += bf2f(v.x); a1 += bf2f(v.y); a2 += bf2f(v.z); a3 += bf2f(v.w);
    }
    float sc = invdeg[node];
    ushort4 o;
    o.x = f2bf(a0 * sc); o.y = f2bf(a1 * sc); o.z = f2bf(a2 * sc); o.w = f2bf(a3 * sc);
    *(ushort4*)(neigh + (size_t)node * NDIM + lane * 4) = o;
}

// ---------------- fused dual-source bf16 MFMA GEMM ----------------
// C = A1@B1 + A2@B2 + bias (+relu).  A: Mx256 bf16 row-major. Bt: 256x256 bf16,
// Bt[n][k] = B[k][n].  128x128 tile, BK=32, 4 waves each owning 64x64.

template <int RELU, int WB>
__global__ __launch_bounds__(256) void k_gemm(
        const uint16_t* __restrict__ A1, const uint16_t* __restrict__ B1t,
        const uint16_t* __restrict__ A2, const uint16_t* __restrict__ B2t,
        const float* __restrict__ bias, float* __restrict__ C,
        uint16_t* __restrict__ Cb, int M) {
    constexpr int LST = 40;   // LDS row stride in bf16 (80B): quarter-wave b128 spans all banks
    __shared__ __align__(16) bf16_t As[128 * LST];
    __shared__ __align__(16) bf16_t Bs[128 * LST];
    int tid  = threadIdx.x;
    int w    = tid >> 6, lane = tid & 63;
    int wm   = w >> 1,   wn   = w & 1;
    int row0 = blockIdx.x * 128;
    int col0 = blockIdx.y * 128;

    f32x4 acc[4][4];
#pragma unroll
    for (int m = 0; m < 4; ++m)
#pragma unroll
        for (int n = 0; n < 4; ++n)
            acc[m][n] = (f32x4){0.f, 0.f, 0.f, 0.f};

    // staging: unit u in [0,512): row = u>>2, 16B-seg = u&3; thread owns u=tid, tid+256
    int r0s = tid >> 2, s0s = tid & 3;      // rows 0..63
    int r1s = r0s + 64, s1s = s0s;          // rows 64..127
    int kseg = lane >> 4;                   // 0..3 (8 k-elems each)
    int rr   = lane & 15;

    for (int pair = 0; pair < 2; ++pair) {
        const uint16_t* A  = pair ? A2 : A1;
        const uint16_t* Bt = pair ? B2t : B1t;
        for (int k0 = 0; k0 < NDIM; k0 += 32) {
            int gra0 = min(row0 + r0s, M - 1);
            int gra1 = min(row0 + r1s, M - 1);
            uint4 va0 = *(const uint4*)(A  + (size_t)gra0 * NDIM + k0 + s0s * 8);
            uint4 va1 = *(const uint4*)(A  + (size_t)gra1 * NDIM + k0 + s1s * 8);
            uint4 vb0 = *(const uint4*)(Bt + (size_t)(col0 + r0s) * NDIM + k0 + s0s * 8);
            uint4 vb1 = *(const uint4*)(Bt + (size_t)(col0 + r1s) * NDIM + k0 + s1s * 8);
            __syncthreads();   // previous iter's LDS reads complete
            *(uint4*)(As + r0s * LST + s0s * 8) = va0;
            *(uint4*)(As + r1s * LST + s1s * 8) = va1;
            *(uint4*)(Bs + r0s * LST + s0s * 8) = vb0;
            *(uint4*)(Bs + r1s * LST + s1s * 8) = vb1;
            __syncthreads();

            bf16x8 af[4], bfr[4];
#pragma unroll
            for (int m = 0; m < 4; ++m)
                af[m] = *(const bf16x8*)(As + (wm * 64 + m * 16 + rr) * LST + kseg * 8);
#pragma unroll
            for (int n = 0; n < 4; ++n)
                bfr[n] = *(const bf16x8*)(Bs + (wn * 64 + n * 16 + rr) * LST + kseg * 8);
#pragma unroll
            for (int m = 0; m < 4; ++m)
#pragma unroll
                for (int n = 0; n < 4; ++n)
                    acc[m][n] = __builtin_amdgcn_mfma_f32_16x16x32_bf16(
                        af[m], bfr[n], acc[m][n], 0, 0, 0);
        }
    }

    // epilogue: D row = (lane>>4)*4 + reg, col = lane&15
    int rbase = (lane >> 4) * 4;
    int cc    = lane & 15;
#pragma unroll
    for (int n = 0; n < 4; ++n) {
        int col = col0 + wn * 64 + n * 16 + cc;
        float bb = bias[col];
#pragma unroll
        for (int m = 0; m < 4; ++m) {
#pragma unroll
            for (int r = 0; r < 4; ++r) {
                int row = row0 + wm * 64 + m * 16 + rbase + r;
                if (row < M) {
                    float o = acc[m][n][r] + bb;
                    if (RELU) o = fmaxf(o, 0.f);
                    C[(size_t)row * NDIM + col] = o;
                    if (WB) Cb[(size_t)row * NDIM + col] = f2bf(o);
                }
            }
        }
    }
}

__global__ void k_copy(const float4* __restrict__ in, float4* __restrict__ out, int n4) {
    int i = blockIdx.x * blockDim.x + threadIdx.x;
    if (i < n4) out[i] = in[i];
}

// ---------------- launch ----------------

extern "C" void kernel_launch(void* const* d_in, const int* in_sizes, int n_in,
                              void* d_out, int out_size, void* d_ws, size_t ws_size,
                              hipStream_t stream) {
    const float* feat = (const float*)d_in[0];
    const int*   src  = (const int*)d_in[1];
    const int*   dst  = (const int*)d_in[2];
    const float* Ws0  = (const float*)d_in[3];
    const float* Wn0  = (const float*)d_in[4];
    const float* b0   = (const float*)d_in[5];
    const float* Ws1  = (const float*)d_in[6];
    const float* Wn1  = (const float*)d_in[7];
    const float* b1   = (const float*)d_in[8];

    const int N = in_sizes[0] / NDIM;   // 100000
    const int E = in_sizes[1];          // 1600000

    float* out    = (float*)d_out;
    float* out_x  = out;
    float* out_a1 = out + (size_t)N * NDIM;
    float* out_h2 = out + 2 * (size_t)N * NDIM;

    // bf16 scratch inside not-yet-final output regions (each f32 region fits 2 bf16 buffers)
    uint16_t* featb   = (uint16_t*)out_h2;                       // dead after gemm1... used by aggr1+gemm1
    uint16_t* neigh1b = (uint16_t*)out_h2 + (size_t)N * NDIM;    // dead after gemm1
    uint16_t* a1b     = (uint16_t*)out_x;                        // written by gemm1, read by aggr2+gemm2
    uint16_t* neigh2b = (uint16_t*)out_x + (size_t)N * NDIM;     // dead after gemm2

    // ws: deg | offsets | cursor | invdeg | partial | srcsorted | 4 x Wt
    int*      deg       = (int*)d_ws;
    int*      offsets   = deg + N;
    int*      cursor    = offsets + N;
    float*    invdeg    = (float*)(cursor + N);
    int*      partial   = (int*)(invdeg + N);
    int*      srcsorted = partial + 512;
    uint16_t* Wt        = (uint16_t*)(srcsorted + E);
    uint16_t* Ws0t = Wt;
    uint16_t* Wn0t = Wt + 1 * NDIM * NDIM;
    uint16_t* Ws1t = Wt + 2 * NDIM * NDIM;
    uint16_t* Wn1t = Wt + 3 * NDIM * NDIM;

    hipMemsetAsync(deg, 0, (size_t)N * sizeof(int), stream);

    int nb = (N + 255) / 256;
    k_deg<<<(E + 255) / 256, 256, 0, stream>>>(dst, deg, E);
    k_partial<<<nb, 256, 0, stream>>>(deg, partial, N);
    k_scan_partial<<<1, 512, 0, stream>>>(partial, nb);
    k_scan_block<<<nb, 256, 0, stream>>>(deg, partial, offsets, cursor, invdeg, N);
    k_place<<<(E + 255) / 256, 256, 0, stream>>>(src, dst, cursor, srcsorted, E);

    k_wt<<<NDIM, NDIM, 0, stream>>>(Ws0, Ws0t);
    k_wt<<<NDIM, NDIM, 0, stream>>>(Wn0, Wn0t);
    k_wt<<<NDIM, NDIM, 0, stream>>>(Ws1, Ws1t);
    k_wt<<<NDIM, NDIM, 0, stream>>>(Wn1, Wn1t);

    int n4 = N * NDIM / 4;
    k_cvt<<<(n4 + 255) / 256, 256, 0, stream>>>((const float4*)feat, (ushort4*)featb, n4);

    dim3 gg((N + 127) / 128, NDIM / 128);

    // layer 1
    k_aggr<<<(N + 3) / 4, 256, 0, stream>>>(featb, srcsorted, offsets, deg, invdeg, neigh1b, N);
    k_gemm<1, 1><<<gg, 256, 0, stream>>>(featb, Ws0t, neigh1b, Wn0t, b0, out_a1, a1b, N);

    // layer 2
    k_aggr<<<(N + 3) / 4, 256, 0, stream>>>(a1b, srcsorted, offsets, deg, invdeg, neigh2b, N);
    k_gemm<0, 0><<<gg, 256, 0, stream>>>(a1b, Ws1t, neigh2b, Wn1t, b1, out_h2, nullptr, N);

    // feat passthrough last (frees out_x region)
    k_copy<<<(n4 + 255) / 256, 256, 0, stream>>>((const float4*)feat, (float4*)out_x, n4);
}

// Round 3
// 980.877 us; speedup vs baseline: 1.7226x; 1.0174x over previous
//
#include <hip/hip_runtime.h>
#include <hip/hip_bf16.h>
#include <stdint.h>

#define NDIM 256

typedef __bf16 bf16_t;
typedef __bf16 bf16x8 __attribute__((ext_vector_type(8)));
typedef float f32x4 __attribute__((ext_vector_type(4)));

__device__ __forceinline__ float bf2f(uint16_t u) {
    union { uint32_t i; float f; } v; v.i = ((uint32_t)u) << 16; return v.f;
}
__device__ __forceinline__ uint16_t f2bf(float f) {
    union { float f; uint32_t i; } v; v.f = f;
    uint32_t r = v.i + 0x7fff + ((v.i >> 16) & 1);
    return (uint16_t)(r >> 16);
}

// ---------------- CSR build ----------------

__global__ void k_deg(const int* __restrict__ dst, int* __restrict__ deg, int E) {
    int i = blockIdx.x * blockDim.x + threadIdx.x;
    if (i < E) atomicAdd(&deg[dst[i]], 1);
}

__global__ void k_partial(const int* __restrict__ deg, int* __restrict__ partial, int N) {
    __shared__ int sm[256];
    int i = blockIdx.x * 256 + threadIdx.x;
    sm[threadIdx.x] = (i < N) ? deg[i] : 0;
    __syncthreads();
    for (int s = 128; s > 0; s >>= 1) {
        if (threadIdx.x < s) sm[threadIdx.x] += sm[threadIdx.x + s];
        __syncthreads();
    }
    if (threadIdx.x == 0) partial[blockIdx.x] = sm[0];
}

__global__ void k_scan_partial(int* partial, int nb) {
    __shared__ int sm[512];
    int t = threadIdx.x;
    int v = (t < nb) ? partial[t] : 0;
    sm[t] = v;
    __syncthreads();
    for (int off = 1; off < 512; off <<= 1) {
        int u = (t >= off) ? sm[t - off] : 0;
        __syncthreads();
        sm[t] += u;
        __syncthreads();
    }
    if (t < nb) partial[t] = sm[t] - v;   // exclusive
}

__global__ void k_scan_block(const int* __restrict__ deg, const int* __restrict__ partial,
                             int* __restrict__ offsets, int* __restrict__ cursor,
                             float* __restrict__ invdeg, int N) {
    __shared__ int sm[256];
    int t = threadIdx.x;
    int i = blockIdx.x * 256 + t;
    int v = (i < N) ? deg[i] : 0;
    sm[t] = v;
    __syncthreads();
    for (int off = 1; off < 256; off <<= 1) {
        int u = (t >= off) ? sm[t - off] : 0;
        __syncthreads();
        sm[t] += u;
        __syncthreads();
    }
    if (i < N) {
        int excl = sm[t] - v + partial[blockIdx.x];
        offsets[i] = excl;
        cursor[i]  = excl;
        invdeg[i]  = (v > 0) ? (1.0f / (float)v) : 0.0f;
    }
}

__global__ void k_place(const int* __restrict__ src, const int* __restrict__ dst,
                        int* __restrict__ cursor, int* __restrict__ srcsorted, int E) {
    int i = blockIdx.x * blockDim.x + threadIdx.x;
    if (i < E) {
        int p = atomicAdd(&cursor[dst[i]], 1);
        srcsorted[p] = src[i];
    }
}

// ---------------- conversions ----------------

__global__ void k_cvt(const float4* __restrict__ in, ushort4* __restrict__ out, int n4) {
    int i = blockIdx.x * blockDim.x + threadIdx.x;
    if (i < n4) {
        float4 v = in[i];
        ushort4 o;
        o.x = f2bf(v.x); o.y = f2bf(v.y); o.z = f2bf(v.z); o.w = f2bf(v.w);
        out[i] = o;
    }
}

// feat -> f32 passthrough copy + bf16 copy, one read
__global__ void k_cvtcopy(const float4* __restrict__ in, float4* __restrict__ outf,
                          ushort4* __restrict__ outb, int n4) {
    int i = blockIdx.x * blockDim.x + threadIdx.x;
    if (i < n4) {
        float4 v = in[i];
        outf[i] = v;
        ushort4 o;
        o.x = f2bf(v.x); o.y = f2bf(v.y); o.z = f2bf(v.z); o.w = f2bf(v.w);
        outb[i] = o;
    }
}

// 4 weights transposed+converted in one launch: W[k][n] f32 -> Wt[n][k] bf16
__global__ void k_wt4(const float* __restrict__ W0, const float* __restrict__ W1,
                      const float* __restrict__ W2, const float* __restrict__ W3,
                      uint16_t* __restrict__ Wt) {
    int which = blockIdx.y;
    const float* W = (which == 0) ? W0 : (which == 1) ? W1 : (which == 2) ? W2 : W3;
    uint16_t* O = Wt + (size_t)which * NDIM * NDIM;
    int n = blockIdx.x, k = threadIdx.x;
    O[n * NDIM + k] = f2bf(W[k * NDIM + n]);
}

// ---------------- aggregation ----------------
// One wave per dst node. Coalesced 64-wide index load, indices distributed via
// __shfl (no memory chain). Half-wave row ownership: 32 lanes x 16B per row,
// two edges in flight per step; final cross-half combine via shfl_xor(32).

__global__ __launch_bounds__(256) void k_aggr(
        const uint16_t* __restrict__ x, const int* __restrict__ srcsorted,
        const int* __restrict__ offsets, const int* __restrict__ deg,
        const float* __restrict__ invdeg, uint16_t* __restrict__ neigh, int N) {
    int node = blockIdx.x * 4 + (threadIdx.x >> 6);
    if (node >= N) return;
    int lane = threadIdx.x & 63;
    int half = lane >> 5;          // 0/1: which edge parity this lane handles
    int l32  = lane & 31;          // 16B segment within row
    int beg = offsets[node];
    int d   = deg[node];

    float acc[8] = {0.f, 0.f, 0.f, 0.f, 0.f, 0.f, 0.f, 0.f};

    for (int base = 0; base < d; base += 64) {
        int rem = d - base; if (rem > 64) rem = 64;
        int il = (lane < rem) ? srcsorted[beg + base + lane] : 0;
#pragma unroll 4
        for (int j = half; j < rem; j += 2) {
            int s = __shfl(il, j);
            ushort4 v = *(const ushort4*)(x + (size_t)s * NDIM + l32 * 8);
            uint16_t e0 = v.x, e1 = v.y, e2 = v.z, e3 = v.w;
            // ushort4 = 4x16b; we need 8 bf16 -> load as uint4 instead
            (void)e0; (void)e1; (void)e2; (void)e3;
        }
        // NOTE: replaced below with uint4 path
        break;
    }

    // --- real loop (uint4 = 8 bf16 per lane) ---
    acc[0] = acc[1] = acc[2] = acc[3] = acc[4] = acc[5] = acc[6] = acc[7] = 0.f;
    for (int base = 0; base < d; base += 64) {
        int rem = d - base; if (rem > 64) rem = 64;
        int il = (lane < rem) ? srcsorted[beg + base + lane] : 0;
#pragma unroll 4
        for (int j = half; j < rem; j += 2) {
            int s = __shfl(il, j);
            uint4 v = *(const uint4*)(x + (size_t)s * NDIM + l32 * 8);
            acc[0] += bf2f((uint16_t)(v.x & 0xffff));
            acc[1] += bf2f((uint16_t)(v.x >> 16));
            acc[2] += bf2f((uint16_t)(v.y & 0xffff));
            acc[3] += bf2f((uint16_t)(v.y >> 16));
            acc[4] += bf2f((uint16_t)(v.z & 0xffff));
            acc[5] += bf2f((uint16_t)(v.z >> 16));
            acc[6] += bf2f((uint16_t)(v.w & 0xffff));
            acc[7] += bf2f((uint16_t)(v.w >> 16));
        }
    }

#pragma unroll
    for (int c = 0; c < 8; ++c) acc[c] += __shfl_xor(acc[c], 32);

    if (half == 0) {
        float sc = invdeg[node];
        uint4 o;
        o.x = (uint32_t)f2bf(acc[0] * sc) | ((uint32_t)f2bf(acc[1] * sc) << 16);
        o.y = (uint32_t)f2bf(acc[2] * sc) | ((uint32_t)f2bf(acc[3] * sc) << 16);
        o.z = (uint32_t)f2bf(acc[4] * sc) | ((uint32_t)f2bf(acc[5] * sc) << 16);
        o.w = (uint32_t)f2bf(acc[6] * sc) | ((uint32_t)f2bf(acc[7] * sc) << 16);
        *(uint4*)(neigh + (size_t)node * NDIM + l32 * 8) = o;
    }
}

// ---------------- fused dual-source bf16 MFMA GEMM (unchanged from round 2) ----------------

template <int RELU, int WB>
__global__ __launch_bounds__(256) void k_gemm(
        const uint16_t* __restrict__ A1, const uint16_t* __restrict__ B1t,
        const uint16_t* __restrict__ A2, const uint16_t* __restrict__ B2t,
        const float* __restrict__ bias, float* __restrict__ C,
        uint16_t* __restrict__ Cb, int M) {
    constexpr int LST = 40;
    __shared__ __align__(16) bf16_t As[128 * LST];
    __shared__ __align__(16) bf16_t Bs[128 * LST];
    int tid  = threadIdx.x;
    int w    = tid >> 6, lane = tid & 63;
    int wm   = w >> 1,   wn   = w & 1;
    int row0 = blockIdx.x * 128;
    int col0 = blockIdx.y * 128;

    f32x4 acc[4][4];
#pragma unroll
    for (int m = 0; m < 4; ++m)
#pragma unroll
        for (int n = 0; n < 4; ++n)
            acc[m][n] = (f32x4){0.f, 0.f, 0.f, 0.f};

    int r0s = tid >> 2, s0s = tid & 3;
    int r1s = r0s + 64, s1s = s0s;
    int kseg = lane >> 4;
    int rr   = lane & 15;

    for (int pair = 0; pair < 2; ++pair) {
        const uint16_t* A  = pair ? A2 : A1;
        const uint16_t* Bt = pair ? B2t : B1t;
        for (int k0 = 0; k0 < NDIM; k0 += 32) {
            int gra0 = min(row0 + r0s, M - 1);
            int gra1 = min(row0 + r1s, M - 1);
            uint4 va0 = *(const uint4*)(A  + (size_t)gra0 * NDIM + k0 + s0s * 8);
            uint4 va1 = *(const uint4*)(A  + (size_t)gra1 * NDIM + k0 + s1s * 8);
            uint4 vb0 = *(const uint4*)(Bt + (size_t)(col0 + r0s) * NDIM + k0 + s0s * 8);
            uint4 vb1 = *(const uint4*)(Bt + (size_t)(col0 + r1s) * NDIM + k0 + s1s * 8);
            __syncthreads();
            *(uint4*)(As + r0s * LST + s0s * 8) = va0;
            *(uint4*)(As + r1s * LST + s1s * 8) = va1;
            *(uint4*)(Bs + r0s * LST + s0s * 8) = vb0;
            *(uint4*)(Bs + r1s * LST + s1s * 8) = vb1;
            __syncthreads();

            bf16x8 af[4], bfr[4];
#pragma unroll
            for (int m = 0; m < 4; ++m)
                af[m] = *(const bf16x8*)(As + (wm * 64 + m * 16 + rr) * LST + kseg * 8);
#pragma unroll
            for (int n = 0; n < 4; ++n)
                bfr[n] = *(const bf16x8*)(Bs + (wn * 64 + n * 16 + rr) * LST + kseg * 8);
#pragma unroll
            for (int m = 0; m < 4; ++m)
#pragma unroll
                for (int n = 0; n < 4; ++n)
                    acc[m][n] = __builtin_amdgcn_mfma_f32_16x16x32_bf16(
                        af[m], bfr[n], acc[m][n], 0, 0, 0);
        }
    }

    int rbase = (lane >> 4) * 4;
    int cc    = lane & 15;
#pragma unroll
    for (int n = 0; n < 4; ++n) {
        int col = col0 + wn * 64 + n * 16 + cc;
        float bb = bias[col];
#pragma unroll
        for (int m = 0; m < 4; ++m) {
#pragma unroll
            for (int r = 0; r < 4; ++r) {
                int row = row0 + wm * 64 + m * 16 + rbase + r;
                if (row < M) {
                    float o = acc[m][n][r] + bb;
                    if (RELU) o = fmaxf(o, 0.f);
                    C[(size_t)row * NDIM + col] = o;
                    if (WB) Cb[(size_t)row * NDIM + col] = f2bf(o);
                }
            }
        }
    }
}

__global__ void k_copy(const float4* __restrict__ in, float4* __restrict__ out, int n4) {
    int i = blockIdx.x * blockDim.x + threadIdx.x;
    if (i < n4) out[i] = in[i];
}

// ---------------- launch ----------------

extern "C" void kernel_launch(void* const* d_in, const int* in_sizes, int n_in,
                              void* d_out, int out_size, void* d_ws, size_t ws_size,
                              hipStream_t stream) {
    const float* feat = (const float*)d_in[0];
    const int*   src  = (const int*)d_in[1];
    const int*   dst  = (const int*)d_in[2];
    const float* Ws0  = (const float*)d_in[3];
    const float* Wn0  = (const float*)d_in[4];
    const float* b0   = (const float*)d_in[5];
    const float* Ws1  = (const float*)d_in[6];
    const float* Wn1  = (const float*)d_in[7];
    const float* b1   = (const float*)d_in[8];

    const int N = in_sizes[0] / NDIM;   // 100000
    const int E = in_sizes[1];          // 1600000

    float* out    = (float*)d_out;
    float* out_x  = out;
    float* out_a1 = out + (size_t)N * NDIM;
    float* out_h2 = out + 2 * (size_t)N * NDIM;

    // ws layout: deg | offsets | cursor | invdeg | partial | srcsorted | Wt x4 | bf16 bufs x4
    int*      deg       = (int*)d_ws;
    int*      offsets   = deg + N;
    int*      cursor    = offsets + N;
    float*    invdeg    = (float*)(cursor + N);
    int*      partial   = (int*)(invdeg + N);
    int*      srcsorted = partial + 512;
    uint16_t* Wt        = (uint16_t*)(srcsorted + E);
    uint16_t* Ws0t = Wt;
    uint16_t* Wn0t = Wt + 1 * (size_t)NDIM * NDIM;
    uint16_t* Ws1t = Wt + 2 * (size_t)NDIM * NDIM;
    uint16_t* Wn1t = Wt + 3 * (size_t)NDIM * NDIM;
    uint16_t* wsbuf = Wt + 4 * (size_t)NDIM * NDIM;

    size_t NK = (size_t)N * NDIM;
    size_t need = ((char*)(wsbuf + 4 * NK)) - (char*)d_ws;
    bool ws_ok = ws_size >= need;

    uint16_t *featb, *neigh1b, *a1b, *neigh2b;
    if (ws_ok) {
        featb   = wsbuf;
        neigh1b = wsbuf + NK;
        a1b     = wsbuf + 2 * NK;
        neigh2b = wsbuf + 3 * NK;
    } else {
        featb   = (uint16_t*)out_h2;
        neigh1b = (uint16_t*)out_h2 + NK;
        a1b     = (uint16_t*)out_x;
        neigh2b = (uint16_t*)out_x + NK;
    }

    hipMemsetAsync(deg, 0, (size_t)N * sizeof(int), stream);

    int nb = (N + 255) / 256;
    k_deg<<<(E + 255) / 256, 256, 0, stream>>>(dst, deg, E);
    k_partial<<<nb, 256, 0, stream>>>(deg, partial, N);
    k_scan_partial<<<1, 512, 0, stream>>>(partial, nb);
    k_scan_block<<<nb, 256, 0, stream>>>(deg, partial, offsets, cursor, invdeg, N);
    k_place<<<(E + 255) / 256, 256, 0, stream>>>(src, dst, cursor, srcsorted, E);

    dim3 gw(NDIM, 4);
    k_wt4<<<gw, NDIM, 0, stream>>>(Ws0, Wn0, Ws1, Wn1, Wt);

    int n4 = N * NDIM / 4;
    if (ws_ok) {
        // feat passthrough + bf16 conversion in one read, up front
        k_cvtcopy<<<(n4 + 255) / 256, 256, 0, stream>>>(
            (const float4*)feat, (float4*)out_x, (ushort4*)featb, n4);
    } else {
        k_cvt<<<(n4 + 255) / 256, 256, 0, stream>>>((const float4*)feat, (ushort4*)featb, n4);
    }

    dim3 gg((N + 127) / 128, NDIM / 128);

    // layer 1
    k_aggr<<<(N + 3) / 4, 256, 0, stream>>>(featb, srcsorted, offsets, deg, invdeg, neigh1b, N);
    k_gemm<1, 1><<<gg, 256, 0, stream>>>(featb, Ws0t, neigh1b, Wn0t, b0, out_a1, a1b, N);

    // layer 2
    k_aggr<<<(N + 3) / 4, 256, 0, stream>>>(a1b, srcsorted, offsets, deg, invdeg, neigh2b, N);
    k_gemm<0, 0><<<gg, 256, 0, stream>>>(a1b, Ws1t, neigh2b, Wn1t, b1, out_h2, nullptr, N);

    if (!ws_ok) {
        k_copy<<<(n4 + 255) / 256, 256, 0, stream>>>((const float4*)feat, (float4*)out_x, n4);
    }
}